// Round 10
// baseline (76.167 us; speedup 1.0000x reference)
//
#include <hip/hip_runtime.h>

#define N_CLS 8192
#define DIMB  1024          // bytes per row (fp4: 0.5 B/elem, 2048 elems)
#define BKB   128           // K-tile bytes per row = 256 elements
#define NBT   32            // 8192/256 tile grid
#define NTILES 528          // NBT*(NBT+1)/2 upper-tri 256x256 tiles
#define NT    8             // DIMB/BKB K-tiles

typedef __attribute__((ext_vector_type(16))) float f32x16;
typedef __attribute__((ext_vector_type(8)))  int   i32x8;

__device__ __forceinline__ void load16(const char* g, char* l) {
    __builtin_amdgcn_global_load_lds(
        (const __attribute__((address_space(1))) void*)g,
        (__attribute__((address_space(3))) void*)l, 16, 0, 0);
}

// ---- e2m1 encode: nearest of {0,.5,1,1.5,2,3,4,6} with sign ----
__device__ __forceinline__ unsigned enc1(float v, float sc) {
    float a = fabsf(v) * sc;
    unsigned c = (a >= 0.25f) + (a >= 0.75f) + (a >= 1.25f) + (a >= 1.75f) +
                 (a >= 2.5f)  + (a >= 3.5f)  + (a >= 5.0f);
    return c | ((__float_as_uint(v) >> 28) & 8u);
}
__device__ __forceinline__ unsigned short enc4(float4 v, float sc) {
    return (unsigned short)(enc1(v.x, sc) | (enc1(v.y, sc) << 4) |
                            (enc1(v.z, sc) << 8) | (enc1(v.w, sc) << 12));
}

// ------- kernel 1: wave-per-row L2-normalize, scale x64, quantize to e2m1 -------
__global__ __launch_bounds__(256) void normalize_rows(const float* __restrict__ x,
                                                      unsigned char* __restrict__ xq) {
    const int wid = threadIdx.x >> 6, lane = threadIdx.x & 63;
    const int row = blockIdx.x * 4 + wid;
    const float4* xr = reinterpret_cast<const float4*>(x + (size_t)row * 2048);
    float4 v[8];
    float s = 0.0f;
#pragma unroll
    for (int k = 0; k < 8; ++k) {
        v[k] = xr[lane + 64 * k];
        s += v[k].x*v[k].x + v[k].y*v[k].y + v[k].z*v[k].z + v[k].w*v[k].w;
    }
#pragma unroll
    for (int off = 32; off > 0; off >>= 1) s += __shfl_down(s, off);
    s = __shfl(s, 0);
    const float sc = 64.0f / fmaxf(sqrtf(s), 1e-12f);
    unsigned short* orow = reinterpret_cast<unsigned short*>(xq + (size_t)row * DIMB);
#pragma unroll
    for (int k = 0; k < 8; ++k) orow[lane + 64 * k] = enc4(v[k], sc);
}

// read one 16-byte (K=64, fp4) fragment from a swizzled LDS row
__device__ __forceinline__ int4 rd16(const char* rowp, int cc, int swz) {
    return *reinterpret_cast<const int4*>(rowp + (((cc) ^ swz) << 4));
}
// fp4 operand: 16B live in dwords 0..3; upper half ignored for FMT=fp4 (dup)
__device__ __forceinline__ i32x8 op4(int4 d) {
    i32x8 r;
    r[0] = d.x; r[1] = d.y; r[2] = d.z; r[3] = d.w;
    r[4] = d.x; r[5] = d.y; r[6] = d.z; r[7] = d.w;
    return r;
}
#define MFMA4(A, B, C) __builtin_amdgcn_mfma_scale_f32_32x32x64_f8f6f4( \
    (A), (B), (C), 4, 4, 0, 0x7F7F7F7F, 0, 0x7F7F7F7F)

// ---- kernel 2: 256x256 MX-fp4 gram tile, 4 waves of 128x128, 1 block/CU ----
__global__ __launch_bounds__(256, 1) void gram_tile(const char* __restrict__ xq,
                                                    float* __restrict__ partials) {
    constexpr int SLOT = 256 * BKB;            // 32 KiB per matrix per buffer

    __shared__ __align__(16) char As[2 * SLOT];   // 64 KiB
    __shared__ __align__(16) char Bs[2 * SLOT];   // 64 KiB
    __shared__ float red[4];

    int bi = 0, rem = blockIdx.x;               // triangle decode, bi <= bj
    while (rem >= NBT - bi) { rem -= NBT - bi; ++bi; }
    const int bj = bi + rem;

    const int tid = threadIdx.x;
    const int lane = tid & 63, wid = tid >> 6;
    const int wr = wid >> 1, wc = wid & 1;      // wave grid 2 x 2, each 128x128

    // staging (pre-swizzled global source; linear LDS dest [256][128])
    const int srow = lane >> 3;                       // 0..7 within an 8-row call
    const int gch  = ((lane & 7) ^ srow) << 4;        // involutive 16B-chunk XOR
    const char* gA = xq + (size_t)(bi * 256 + wid * 64 + srow) * DIMB + gch;
    const char* gB = xq + (size_t)(bj * 256 + wid * 64 + srow) * DIMB + gch;

    auto stageA = [&](int tt, int s) {
#pragma unroll
        for (int q = 0; q < 8; ++q)
            load16(gA + (size_t)(q * 8) * DIMB + tt * BKB,
                   &As[s * SLOT + wid * 8192 + q * 1024]);
    };
    auto stageB = [&](int tt, int s) {
#pragma unroll
        for (int q = 0; q < 8; ++q)
            load16(gB + (size_t)(q * 8) * DIMB + tt * BKB,
                   &Bs[s * SLOT + wid * 8192 + q * 1024]);
    };

    const int lr = lane & 31, hi = lane >> 5, swz = lane & 7;

    f32x16 acc[4][4];
#pragma unroll
    for (int m = 0; m < 4; ++m)
#pragma unroll
        for (int n = 0; n < 4; ++n)
#pragma unroll
            for (int r = 0; r < 16; ++r) acc[m][n][r] = 0.0f;

    stageA(0, 0); stageB(0, 0);
    __syncthreads();

#define READ_S(AV, BV, S)                                                    \
    do {                                                                     \
        _Pragma("unroll")                                                    \
        for (int m = 0; m < 4; ++m)                                          \
            AV[m] = rd16(arow + m * 32 * BKB, 2 * (S) + hi, swz);            \
        _Pragma("unroll")                                                    \
        for (int n = 0; n < 4; ++n)                                          \
            BV[n] = rd16(brow + n * 32 * BKB, 2 * (S) + hi, swz);            \
    } while (0)
#define MFMA_S(AV, BV)                                                       \
    do {                                                                     \
        _Pragma("unroll")                                                    \
        for (int m = 0; m < 4; ++m)                                          \
            _Pragma("unroll")                                                \
            for (int n = 0; n < 4; ++n)                                      \
                acc[m][n] = MFMA4(op4(AV[m]), op4(BV[n]), acc[m][n]);        \
    } while (0)

    for (int t = 0; t < NT; ++t) {
        const char* arow = &As[(t & 1) * SLOT] + (wr * 128 + lr) * BKB;
        const char* brow = &Bs[(t & 1) * SLOT] + (wc * 128 + lr) * BKB;
        const int ns = (t & 1) ^ 1;
        const bool st = (t + 1 < NT);

        int4 aC[4], bC[4], aN[4], bN[4];
        READ_S(aC, bC, 0);
        if (st) stageA(t + 1, ns);      // issue next-tile loads early
        READ_S(aN, bN, 1);
        MFMA_S(aC, bC);
        if (st) stageB(t + 1, ns);
        READ_S(aC, bC, 2);
        MFMA_S(aN, bN);
        READ_S(aN, bN, 3);
        MFMA_S(aC, bC);
        MFMA_S(aN, bN);

        __syncthreads();                // drains vmcnt+lgkmcnt; stages issued ~2000 cyc ago
    }
#undef READ_S
#undef MFMA_S

    // epilogue: raw dot = 4096*g (scale 64^2); exp(-max(2-2g,0)) = exp(min(raw/2048-2,0))
    float s = 0.0f;
#pragma unroll
    for (int m = 0; m < 4; ++m)
#pragma unroll
        for (int n = 0; n < 4; ++n)
#pragma unroll
            for (int r = 0; r < 16; ++r)
                s += __expf(fminf(acc[m][n][r] * (1.0f / 2048.0f) - 2.0f, 0.0f));
#pragma unroll
    for (int off = 32; off > 0; off >>= 1) s += __shfl_down(s, off);
    if (lane == 0) red[wid] = s;
    __syncthreads();
    if (tid == 0) {
        float tot = red[0] + red[1] + red[2] + red[3];
        partials[blockIdx.x] = (bi == bj ? 1.0f : 2.0f) * tot;
    }
}

// ---------------- kernel 3: reduce partials, scale ----------------
__global__ __launch_bounds__(256) void finalize(const float* __restrict__ partials,
                                                float* __restrict__ out) {
    float s = 0.f;
    for (int i = threadIdx.x; i < NTILES; i += 256) s += partials[i];
#pragma unroll
    for (int off = 32; off > 0; off >>= 1) s += __shfl_down(s, off);
    __shared__ float red[4];
    if ((threadIdx.x & 63) == 0) red[threadIdx.x >> 6] = s;
    __syncthreads();
    if (threadIdx.x == 0)
        out[0] = (red[0] + red[1] + red[2] + red[3]) *
                 (1.0f / (8191.0f * 8192.0f));
}

extern "C" void kernel_launch(void* const* d_in, const int* in_sizes, int n_in,
                              void* d_out, int out_size, void* d_ws, size_t ws_size,
                              hipStream_t stream) {
    const float* x = (const float*)d_in[0];
    float* out = (float*)d_out;
    unsigned char* xq = (unsigned char*)d_ws;                // 8 MB fp4 matrix
    float* partials = (float*)((char*)d_ws + (size_t)N_CLS * DIMB);

    normalize_rows<<<N_CLS / 4, 256, 0, stream>>>(x, xq);
    gram_tile<<<NTILES, 256, 0, stream>>>((const char*)xq, partials);
    finalize<<<1, 256, 0, stream>>>(partials, out);
}

// Round 11
// 67.521 us; speedup vs baseline: 1.1280x; 1.1280x over previous
//
#include <hip/hip_runtime.h>

#define N_CLS 8192
#define DIMB  1024          // bytes per row (fp4: 0.5 B/elem, 2048 elems)
#define BKB   128           // K-tile bytes per row = 256 elements
#define NBT   64            // 8192/128 tile grid
#define NTILES 2080         // NBT*(NBT+1)/2 upper-tri 128x128 tiles
#define NT    8             // DIMB/BKB K-tiles

typedef __attribute__((ext_vector_type(16))) float f32x16;
typedef __attribute__((ext_vector_type(8)))  int   i32x8;

__device__ __forceinline__ void load16(const char* g, char* l) {
    __builtin_amdgcn_global_load_lds(
        (const __attribute__((address_space(1))) void*)g,
        (__attribute__((address_space(3))) void*)l, 16, 0, 0);
}

// ---- e2m1 encode: nearest of {0,.5,1,1.5,2,3,4,6} with sign ----
__device__ __forceinline__ unsigned enc1(float v, float sc) {
    float a = fabsf(v) * sc;
    unsigned c = (a >= 0.25f) + (a >= 0.75f) + (a >= 1.25f) + (a >= 1.75f) +
                 (a >= 2.5f)  + (a >= 3.5f)  + (a >= 5.0f);
    return c | ((__float_as_uint(v) >> 28) & 8u);
}
__device__ __forceinline__ unsigned short enc4(float4 v, float sc) {
    return (unsigned short)(enc1(v.x, sc) | (enc1(v.y, sc) << 4) |
                            (enc1(v.z, sc) << 8) | (enc1(v.w, sc) << 12));
}

// ------- kernel 1: wave-per-row L2-normalize, scale x64, quantize to e2m1 -------
__global__ __launch_bounds__(256) void normalize_rows(const float* __restrict__ x,
                                                      unsigned char* __restrict__ xq) {
    const int wid = threadIdx.x >> 6, lane = threadIdx.x & 63;
    const int row = blockIdx.x * 4 + wid;
    const float4* xr = reinterpret_cast<const float4*>(x + (size_t)row * 2048);
    float4 v[8];
    float s = 0.0f;
#pragma unroll
    for (int k = 0; k < 8; ++k) {
        v[k] = xr[lane + 64 * k];
        s += v[k].x*v[k].x + v[k].y*v[k].y + v[k].z*v[k].z + v[k].w*v[k].w;
    }
#pragma unroll
    for (int off = 32; off > 0; off >>= 1) s += __shfl_down(s, off);
    s = __shfl(s, 0);
    const float sc = 64.0f / fmaxf(sqrtf(s), 1e-12f);
    unsigned short* orow = reinterpret_cast<unsigned short*>(xq + (size_t)row * DIMB);
#pragma unroll
    for (int k = 0; k < 8; ++k) orow[lane + 64 * k] = enc4(v[k], sc);
}

// read one 16-byte (K=64, fp4) fragment from a swizzled LDS row; dup into both halves
__device__ __forceinline__ i32x8 rdfrag4(const char* rowp, int cc, int swz) {
    int4 d = *reinterpret_cast<const int4*>(rowp + (((cc) ^ swz) << 4));
    i32x8 r;
    r[0] = d.x; r[1] = d.y; r[2] = d.z; r[3] = d.w;
    r[4] = d.x; r[5] = d.y; r[6] = d.z; r[7] = d.w;
    return r;
}

#define MFMA4(A, B, C) __builtin_amdgcn_mfma_scale_f32_32x32x64_f8f6f4( \
    (A), (B), (C), 4, 4, 0, 0x7F7F7F7F, 0, 0x7F7F7F7F)

// ---- kernel 2: 128x128 MX-fp4 gram tile, 4 waves of 64x64, single-buffer,
//      ~3 blocks/CU for cross-block latency hiding ----
__global__ __launch_bounds__(256) void gram_tile(const char* __restrict__ xq,
                                                 float* __restrict__ partials) {
    constexpr int SLOT = 128 * BKB;            // 16 KiB per matrix

    __shared__ __align__(16) char As[SLOT];
    __shared__ __align__(16) char Bs[SLOT];
    __shared__ float red[4];

    // bijective XCD-aware swizzle: 2080 = 8 XCDs x 260 blocks exactly
    const int swb = (int)((blockIdx.x & 7) * (NTILES / 8) + (blockIdx.x >> 3));
    int bi = 0, rem = swb;                      // triangle decode, bi <= bj
    while (rem >= NBT - bi) { rem -= NBT - bi; ++bi; }
    const int bj = bi + rem;

    const int tid = threadIdx.x;
    const int lane = tid & 63, wid = tid >> 6;
    const int wr = wid >> 1, wc = wid & 1;      // wave grid 2 x 2, each 64x64

    // staging (pre-swizzled global source; linear LDS dest) — proven pattern
    const int srow = lane >> 3;                       // 0..7 within an 8-row call
    const int gch  = ((lane & 7) ^ srow) << 4;        // involutive 16B-chunk XOR
    const char* gA = xq + (size_t)(bi * 128 + wid * 32 + srow) * DIMB + gch;
    const char* gB = xq + (size_t)(bj * 128 + wid * 32 + srow) * DIMB + gch;

    const int lr = lane & 31, hi = lane >> 5, swz = lane & 7;
    const char* arow = As + (wr * 64 + lr) * BKB;     // single buffer: loop-invariant
    const char* brow = Bs + (wc * 64 + lr) * BKB;

    f32x16 acc[2][2];
#pragma unroll
    for (int m = 0; m < 2; ++m)
#pragma unroll
        for (int n = 0; n < 2; ++n)
#pragma unroll
            for (int r = 0; r < 16; ++r) acc[m][n][r] = 0.0f;

    for (int t = 0; t < NT; ++t) {
        // stage tile t (4+4 x 1KB calls per wave)
#pragma unroll
        for (int q = 0; q < 4; ++q)
            load16(gA + (size_t)(q * 8) * DIMB + t * BKB, &As[wid * 4096 + q * 1024]);
#pragma unroll
        for (int q = 0; q < 4; ++q)
            load16(gB + (size_t)(q * 8) * DIMB + t * BKB, &Bs[wid * 4096 + q * 1024]);
        __syncthreads();                // compiler emits vmcnt(0)+lgkmcnt(0) drain

        // compute: 4 K-slices, compiler-scheduled (no hand fences)
#pragma unroll
        for (int s = 0; s < 4; ++s) {
            i32x8 af[2], bf[2];
#pragma unroll
            for (int m = 0; m < 2; ++m)
                af[m] = rdfrag4(arow + m * 32 * BKB, 2 * s + hi, swz);
#pragma unroll
            for (int n = 0; n < 2; ++n)
                bf[n] = rdfrag4(brow + n * 32 * BKB, 2 * s + hi, swz);
#pragma unroll
            for (int m = 0; m < 2; ++m)
#pragma unroll
                for (int n = 0; n < 2; ++n)
                    acc[m][n] = MFMA4(af[m], bf[n], acc[m][n]);
        }
        __syncthreads();                // all reads of this buffer done before re-stage
    }

    // epilogue: raw dot = 4096*g (scale 64^2); exp(-max(2-2g,0)) = exp(min(raw/2048-2,0))
    float s = 0.0f;
#pragma unroll
    for (int m = 0; m < 2; ++m)
#pragma unroll
        for (int n = 0; n < 2; ++n)
#pragma unroll
            for (int r = 0; r < 16; ++r)
                s += __expf(fminf(acc[m][n][r] * (1.0f / 2048.0f) - 2.0f, 0.0f));
#pragma unroll
    for (int off = 32; off > 0; off >>= 1) s += __shfl_down(s, off);
    if (lane == 0) red[wid] = s;
    __syncthreads();
    if (tid == 0) {
        float tot = red[0] + red[1] + red[2] + red[3];
        partials[blockIdx.x] = (bi == bj ? 1.0f : 2.0f) * tot;
    }
}

// ---------------- kernel 3: reduce partials, scale ----------------
__global__ __launch_bounds__(256) void finalize(const float* __restrict__ partials,
                                                float* __restrict__ out) {
    float s = 0.f;
    for (int i = threadIdx.x; i < NTILES; i += 256) s += partials[i];
#pragma unroll
    for (int off = 32; off > 0; off >>= 1) s += __shfl_down(s, off);
    __shared__ float red[4];
    if ((threadIdx.x & 63) == 0) red[threadIdx.x >> 6] = s;
    __syncthreads();
    if (threadIdx.x == 0)
        out[0] = (red[0] + red[1] + red[2] + red[3]) *
                 (1.0f / (8191.0f * 8192.0f));
}

extern "C" void kernel_launch(void* const* d_in, const int* in_sizes, int n_in,
                              void* d_out, int out_size, void* d_ws, size_t ws_size,
                              hipStream_t stream) {
    const float* x = (const float*)d_in[0];
    float* out = (float*)d_out;
    unsigned char* xq = (unsigned char*)d_ws;                // 8 MB fp4 matrix
    float* partials = (float*)((char*)d_ws + (size_t)N_CLS * DIMB);

    normalize_rows<<<N_CLS / 4, 256, 0, stream>>>(x, xq);
    gram_tile<<<NTILES, 256, 0, stream>>>((const char*)xq, partials);
    finalize<<<1, 256, 0, stream>>>(partials, out);
}